// Round 4
// baseline (844.473 us; speedup 1.0000x reference)
//
#include <hip/hip_runtime.h>
#include <hip/hip_bf16.h>

#define N_TOKENS 2048
#define D_IN 1024
#define D_HID 4096
#define D_OUT 1024
#define NE 8

typedef __attribute__((ext_vector_type(8))) short s16x8;
typedef __attribute__((ext_vector_type(4))) float f32x4;

__device__ inline unsigned short f2bf(float f) {
  union { float f; unsigned u; } v; v.f = f;
  unsigned u = v.u;
  unsigned r = u + 0x7fff + ((u >> 16) & 1);   // round-to-nearest-even
  return (unsigned short)(r >> 16);
}

#define GLDS16(gp, lp)                                                          \
  __builtin_amdgcn_global_load_lds(                                             \
      (const __attribute__((address_space(1))) unsigned int*)(gp),              \
      (__attribute__((address_space(3))) unsigned int*)(lp), 16, 0, 0)

// ---------------------------------------------------------------- router ----
__global__ __launch_bounds__(256) void router_kernel(
    const float* __restrict__ x, const float* __restrict__ Wr,
    const float* __restrict__ br, int* __restrict__ cnt, int* __restrict__ tids,
    int4* __restrict__ meta, float2* __restrict__ tw) {
  int wid = threadIdx.x >> 6, lane = threadIdx.x & 63;
  int n = blockIdx.x * 4 + wid;
  const float* xr = x + (size_t)n * D_IN;
  float acc[NE];
#pragma unroll
  for (int e = 0; e < NE; e++) acc[e] = 0.f;
  for (int i = lane; i < D_IN; i += 64) {
    float xv = xr[i];
    const float4* wr = (const float4*)(Wr + (size_t)i * NE);
    float4 w0 = wr[0], w1 = wr[1];
    acc[0] += xv * w0.x; acc[1] += xv * w0.y;
    acc[2] += xv * w0.z; acc[3] += xv * w0.w;
    acc[4] += xv * w1.x; acc[5] += xv * w1.y;
    acc[6] += xv * w1.z; acc[7] += xv * w1.w;
  }
#pragma unroll
  for (int e = 0; e < NE; e++) {
#pragma unroll
    for (int s = 32; s; s >>= 1) acc[e] += __shfl_xor(acc[e], s, 64);
  }
  if (lane == 0) {
    float lg[NE], p[NE];
    float m = -1e30f;
#pragma unroll
    for (int e = 0; e < NE; e++) { lg[e] = acc[e] + br[e]; m = fmaxf(m, lg[e]); }
    float s = 0.f;
#pragma unroll
    for (int e = 0; e < NE; e++) { p[e] = expf(lg[e] - m); s += p[e]; }
    float inv = 1.f / s;
    int i0 = 0;
#pragma unroll
    for (int e = 1; e < NE; e++) if (lg[e] > lg[i0]) i0 = e;
    int i1 = (i0 == 0) ? 1 : 0;
#pragma unroll
    for (int e = 0; e < NE; e++) if (e != i0 && lg[e] > lg[i1]) i1 = e;
    int p0 = atomicAdd(&cnt[i0], 1);
    int p1 = atomicAdd(&cnt[i1], 1);
    tids[i0 * N_TOKENS + p0] = n;
    tids[i1 * N_TOKENS + p1] = n;
    meta[n] = make_int4(i0, p0, i1, p1);
    tw[n] = make_float2(p[i0] * inv, p[i1] * inv);
  }
}

// ------------------------------------------------------------- conversions ----
__global__ __launch_bounds__(256) void convx_kernel(const float* __restrict__ x,
                                                    short* __restrict__ xb) {
  int i = (blockIdx.x * 256 + threadIdx.x) * 4;
  float4 v = *(const float4*)(x + i);
  short4 o;
  o.x = (short)f2bf(v.x); o.y = (short)f2bf(v.y);
  o.z = (short)f2bf(v.z); o.w = (short)f2bf(v.w);
  *(short4*)(xb + i) = o;
}

// src [R][C] f32 (per expert slab), dst [C][R] bf16
__global__ __launch_bounds__(256) void transconv_kernel(
    const float* __restrict__ src, short* __restrict__ dst, int R, int C) {
  __shared__ float tile[64][65];
  int tx = threadIdx.x & 63, ty = threadIdx.x >> 6;
  size_t eoff = (size_t)blockIdx.z * R * C;
  int r0 = blockIdx.y * 64, c0 = blockIdx.x * 64;
  const float* s = src + eoff + (size_t)r0 * C + c0;
#pragma unroll
  for (int i = 0; i < 16; i++) {
    int r = i * 4 + ty;
    tile[r][tx] = s[(size_t)r * C + tx];
  }
  __syncthreads();
  short* d = dst + eoff + (size_t)c0 * R + r0;
#pragma unroll
  for (int i = 0; i < 16; i++) {
    int c = i * 4 + ty;
    d[(size_t)c * R + tx] = (short)f2bf(tile[tx][c]);
  }
}

// ------------------------------------------------------------------ GEMM1 ----
// H[off_e + t][:] = relu(x[tok] @ W1[e] + b1[e]),  A gathered by token list
__global__ __launch_bounds__(256) void gemm1_kernel(
    const short* __restrict__ xb,   // [2048][1024] bf16
    const short* __restrict__ W1b,  // [8][4096][1024] bf16 (n-major)
    const float* __restrict__ b1,   // [8][4096]
    const int* __restrict__ cnt, const int* __restrict__ tids,
    short* __restrict__ H) {        // [4096][4096] bf16 compact
  const int NT_M = N_TOKENS / 128, NT_N = D_HID / 128;
  int bid = blockIdx.x;
  int e = bid / (NT_M * NT_N);
  int r2 = bid % (NT_M * NT_N);
  int mt = r2 % NT_M, nt = r2 / NT_M;
  int ce = cnt[e];
  if (mt * 128 >= ce) return;
  int off = 0;
  for (int i = 0; i < e; i++) off += cnt[i];

  __shared__ alignas(16) short As[128][64];
  __shared__ alignas(16) short Bs[128][64];

  int lane = threadIdx.x & 63, wid = threadIdx.x >> 6;
  int wr = wid >> 1, wc = wid & 1;

  const int* tlist = tids + e * N_TOKENS + mt * 128;
  const short* agp[4];
#pragma unroll
  for (int c = 0; c < 4; c++) {
    int r = c * 32 + wid * 8 + (lane >> 3);
    int t = (mt * 128 + r < ce) ? tlist[r] : tlist[0];
    agp[c] = xb + (size_t)t * D_IN + (lane & 7) * 8;
  }
  const short* bgp = W1b + (size_t)e * D_HID * D_IN + (size_t)(nt * 128) * D_IN + (lane & 7) * 8;

  f32x4 zero = {0.f, 0.f, 0.f, 0.f};
  f32x4 acc[4][4];
#pragma unroll
  for (int i = 0; i < 4; i++) {
#pragma unroll
    for (int j = 0; j < 4; j++) acc[i][j] = zero;
  }

  for (int ks = 0; ks < D_IN / 64; ks++) {
    int k0 = ks * 64;
#pragma unroll
    for (int c = 0; c < 4; c++) {
      int r = c * 32 + wid * 8 + (lane >> 3);
      GLDS16(agp[c] + k0, &As[c * 32 + wid * 8][0]);
      GLDS16(bgp + (size_t)r * D_IN + k0, &Bs[c * 32 + wid * 8][0]);
    }
    __syncthreads();
#pragma unroll
    for (int kk = 0; kk < 2; kk++) {
      s16x8 a[4], b[4];
#pragma unroll
      for (int i = 0; i < 4; i++)
        a[i] = *(const s16x8*)&As[wr * 64 + i * 16 + (lane & 15)][kk * 32 + (lane >> 4) * 8];
#pragma unroll
      for (int j = 0; j < 4; j++)
        b[j] = *(const s16x8*)&Bs[wc * 64 + j * 16 + (lane & 15)][kk * 32 + (lane >> 4) * 8];
#pragma unroll
      for (int i = 0; i < 4; i++) {
#pragma unroll
        for (int j = 0; j < 4; j++)
          acc[i][j] = __builtin_amdgcn_mfma_f32_16x16x32_bf16(a[i], b[j], acc[i][j], 0, 0, 0);
      }
    }
    __syncthreads();
  }

  int lr = (lane >> 4) * 4, lc = lane & 15;
#pragma unroll
  for (int j = 0; j < 4; j++) {
    int col = nt * 128 + wc * 64 + j * 16 + lc;
    float bias = b1[e * D_HID + col];
#pragma unroll
    for (int i = 0; i < 4; i++) {
#pragma unroll
      for (int r = 0; r < 4; r++) {
        int grow = mt * 128 + wr * 64 + i * 16 + lr + r;
        if (grow < ce) {
          float v = fmaxf(acc[i][j][r] + bias, 0.f);
          H[(size_t)(off + grow) * D_HID + col] = (short)f2bf(v);
        }
      }
    }
  }
}

// ------------------------------------------------------------------ GEMM2 ----
// Y[off_e + t][:] = H[off_e + t] @ W2[e]    (f32 out, bias folded into combine)
__global__ __launch_bounds__(256) void gemm2_kernel(
    const short* __restrict__ H,    // [4096][4096] bf16
    const short* __restrict__ W2b,  // [8][1024][4096] bf16 (n-major)
    const int* __restrict__ cnt,
    float* __restrict__ Y) {        // [4096][1024] f32
  const int NT_M = N_TOKENS / 128, NT_N = D_OUT / 128;
  int bid = blockIdx.x;
  int e = bid / (NT_M * NT_N);
  int r2 = bid % (NT_M * NT_N);
  int mt = r2 % NT_M, nt = r2 / NT_M;
  int ce = cnt[e];
  if (mt * 128 >= ce) return;
  int off = 0;
  for (int i = 0; i < e; i++) off += cnt[i];

  __shared__ alignas(16) short As[128][64];
  __shared__ alignas(16) short Bs[128][64];

  int lane = threadIdx.x & 63, wid = threadIdx.x >> 6;
  int wr = wid >> 1, wc = wid & 1;

  const short* agp[4];
#pragma unroll
  for (int c = 0; c < 4; c++) {
    int r = c * 32 + wid * 8 + (lane >> 3);
    int grow = mt * 128 + r;
    if (grow > ce - 1) grow = ce - 1;
    agp[c] = H + (size_t)(off + grow) * D_HID + (lane & 7) * 8;
  }
  const short* bgp = W2b + (size_t)e * D_OUT * D_HID + (size_t)(nt * 128) * D_HID + (lane & 7) * 8;

  f32x4 zero = {0.f, 0.f, 0.f, 0.f};
  f32x4 acc[4][4];
#pragma unroll
  for (int i = 0; i < 4; i++) {
#pragma unroll
    for (int j = 0; j < 4; j++) acc[i][j] = zero;
  }

  for (int ks = 0; ks < D_HID / 64; ks++) {
    int k0 = ks * 64;
#pragma unroll
    for (int c = 0; c < 4; c++) {
      int r = c * 32 + wid * 8 + (lane >> 3);
      GLDS16(agp[c] + k0, &As[c * 32 + wid * 8][0]);
      GLDS16(bgp + (size_t)r * D_HID + k0, &Bs[c * 32 + wid * 8][0]);
    }
    __syncthreads();
#pragma unroll
    for (int kk = 0; kk < 2; kk++) {
      s16x8 a[4], b[4];
#pragma unroll
      for (int i = 0; i < 4; i++)
        a[i] = *(const s16x8*)&As[wr * 64 + i * 16 + (lane & 15)][kk * 32 + (lane >> 4) * 8];
#pragma unroll
      for (int j = 0; j < 4; j++)
        b[j] = *(const s16x8*)&Bs[wc * 64 + j * 16 + (lane & 15)][kk * 32 + (lane >> 4) * 8];
#pragma unroll
      for (int i = 0; i < 4; i++) {
#pragma unroll
        for (int j = 0; j < 4; j++)
          acc[i][j] = __builtin_amdgcn_mfma_f32_16x16x32_bf16(a[i], b[j], acc[i][j], 0, 0, 0);
      }
    }
    __syncthreads();
  }

  int lr = (lane >> 4) * 4, lc = lane & 15;
#pragma unroll
  for (int j = 0; j < 4; j++) {
    int col = nt * 128 + wc * 64 + j * 16 + lc;
#pragma unroll
    for (int i = 0; i < 4; i++) {
#pragma unroll
      for (int r = 0; r < 4; r++) {
        int grow = mt * 128 + wr * 64 + i * 16 + lr + r;
        if (grow < ce) Y[(size_t)(off + grow) * D_OUT + col] = acc[i][j][r];
      }
    }
  }
}

// ---------------------------------------------------------------- combine ----
__global__ __launch_bounds__(256) void combine_kernel(
    const float* __restrict__ Y, const float* __restrict__ b2,
    const int* __restrict__ cnt, const int4* __restrict__ meta,
    const float2* __restrict__ tw, float* __restrict__ out) {
  int n = blockIdx.x;
  int4 m = meta[n];
  float2 w = tw[n];
  int off0 = 0, off1 = 0;
#pragma unroll
  for (int i = 0; i < NE; i++) {
    int c = cnt[i];
    if (i < m.x) off0 += c;
    if (i < m.z) off1 += c;
  }
  const float4* y0 = (const float4*)(Y + (size_t)(off0 + m.y) * D_OUT);
  const float4* y1 = (const float4*)(Y + (size_t)(off1 + m.w) * D_OUT);
  const float4* g0 = (const float4*)(b2 + (size_t)m.x * D_OUT);
  const float4* g1 = (const float4*)(b2 + (size_t)m.z * D_OUT);
  float4* o = (float4*)(out + (size_t)n * D_OUT);
  int d = threadIdx.x;  // 256 threads x float4 = 1024 floats
  float4 a = y0[d], b = y1[d], ba = g0[d], bb = g1[d];
  float4 r;
  r.x = w.x * (a.x + ba.x) + w.y * (b.x + bb.x);
  r.y = w.x * (a.y + ba.y) + w.y * (b.y + bb.y);
  r.z = w.x * (a.z + ba.z) + w.y * (b.z + bb.z);
  r.w = w.x * (a.w + ba.w) + w.y * (b.w + bb.w);
  o[d] = r;
}

// ----------------------------------------------------------------- launch ----
extern "C" void kernel_launch(void* const* d_in, const int* in_sizes, int n_in,
                              void* d_out, int out_size, void* d_ws, size_t ws_size,
                              hipStream_t stream) {
  const float* x  = (const float*)d_in[0];
  const float* Wr = (const float*)d_in[1];
  const float* br = (const float*)d_in[2];
  const float* W1 = (const float*)d_in[3];
  const float* b1 = (const float*)d_in[4];
  const float* W2 = (const float*)d_in[5];
  const float* b2 = (const float*)d_in[6];
  float* out = (float*)d_out;

  char* ws = (char*)d_ws;
  size_t o = 0;
  auto alloc = [&](size_t bytes) -> void* {
    o = (o + 255) & ~(size_t)255;
    void* p = ws + o;
    o += bytes;
    return p;
  };
  int*    cnt  = (int*)alloc(NE * 4);
  int*    tids = (int*)alloc((size_t)NE * N_TOKENS * 4);
  int4*   meta = (int4*)alloc((size_t)N_TOKENS * 16);
  float2* tw   = (float2*)alloc((size_t)N_TOKENS * 8);
  short*  xb   = (short*)alloc((size_t)N_TOKENS * D_IN * 2);
  short*  W1b  = (short*)alloc((size_t)NE * D_HID * D_IN * 2);
  short*  W2b  = (short*)alloc((size_t)NE * D_OUT * D_HID * 2);
  short*  H    = (short*)alloc((size_t)2 * N_TOKENS * D_HID * 2);
  float*  Y    = (float*)alloc((size_t)2 * N_TOKENS * D_OUT * 4);
  if (o > ws_size) return;  // workspace too small; fail loudly via wrong output

  hipMemsetAsync(cnt, 0, NE * 4, stream);
  router_kernel<<<N_TOKENS / 4, 256, 0, stream>>>(x, Wr, br, cnt, tids, meta, tw);
  convx_kernel<<<(N_TOKENS * D_IN / 4) / 256, 256, 0, stream>>>(x, xb);
  transconv_kernel<<<dim3(D_HID / 64, D_IN / 64, NE), 256, 0, stream>>>(W1, W1b, D_IN, D_HID);
  transconv_kernel<<<dim3(D_OUT / 64, D_HID / 64, NE), 256, 0, stream>>>(W2, W2b, D_HID, D_OUT);
  gemm1_kernel<<<NE * (N_TOKENS / 128) * (D_HID / 128), 256, 0, stream>>>(xb, W1b, b1, cnt, tids, H);
  gemm2_kernel<<<NE * (N_TOKENS / 128) * (D_OUT / 128), 256, 0, stream>>>(H, W2b, cnt, Y);
  combine_kernel<<<N_TOKENS, 256, 0, stream>>>(Y, b2, cnt, meta, tw, out);
}

// Round 6
// 600.721 us; speedup vs baseline: 1.4058x; 1.4058x over previous
//
#include <hip/hip_runtime.h>
#include <hip/hip_bf16.h>

#define N_TOKENS 2048
#define D_IN 1024
#define D_HID 4096
#define D_OUT 1024
#define NE 8

typedef __attribute__((ext_vector_type(8))) short s16x8;
typedef __attribute__((ext_vector_type(4))) float f32x4;

__device__ inline unsigned short f2bf(float f) {
  union { float f; unsigned u; } v; v.f = f;
  unsigned u = v.u;
  unsigned r = u + 0x7fff + ((u >> 16) & 1);   // round-to-nearest-even
  return (unsigned short)(r >> 16);
}

#define GLDS16(gp, lp)                                                          \
  __builtin_amdgcn_global_load_lds(                                             \
      (const __attribute__((address_space(1))) unsigned int*)(gp),              \
      (__attribute__((address_space(3))) unsigned int*)(lp), 16, 0, 0)

// ---------------------------------------------------------------- router ----
__global__ __launch_bounds__(256) void router_kernel(
    const float* __restrict__ x, const float* __restrict__ Wr,
    const float* __restrict__ br, int* __restrict__ cnt, int* __restrict__ tids,
    int4* __restrict__ meta, float2* __restrict__ tw) {
  int wid = threadIdx.x >> 6, lane = threadIdx.x & 63;
  int n = blockIdx.x * 4 + wid;
  const float* xr = x + (size_t)n * D_IN;
  float acc[NE];
#pragma unroll
  for (int e = 0; e < NE; e++) acc[e] = 0.f;
  for (int i = lane; i < D_IN; i += 64) {
    float xv = xr[i];
    const float4* wr = (const float4*)(Wr + (size_t)i * NE);
    float4 w0 = wr[0], w1 = wr[1];
    acc[0] += xv * w0.x; acc[1] += xv * w0.y;
    acc[2] += xv * w0.z; acc[3] += xv * w0.w;
    acc[4] += xv * w1.x; acc[5] += xv * w1.y;
    acc[6] += xv * w1.z; acc[7] += xv * w1.w;
  }
#pragma unroll
  for (int e = 0; e < NE; e++) {
#pragma unroll
    for (int s = 32; s; s >>= 1) acc[e] += __shfl_xor(acc[e], s, 64);
  }
  if (lane == 0) {
    float lg[NE], p[NE];
    float m = -1e30f;
#pragma unroll
    for (int e = 0; e < NE; e++) { lg[e] = acc[e] + br[e]; m = fmaxf(m, lg[e]); }
    float s = 0.f;
#pragma unroll
    for (int e = 0; e < NE; e++) { p[e] = expf(lg[e] - m); s += p[e]; }
    float inv = 1.f / s;
    int i0 = 0;
#pragma unroll
    for (int e = 1; e < NE; e++) if (lg[e] > lg[i0]) i0 = e;
    int i1 = (i0 == 0) ? 1 : 0;
#pragma unroll
    for (int e = 0; e < NE; e++) if (e != i0 && lg[e] > lg[i1]) i1 = e;
    int p0 = atomicAdd(&cnt[i0], 1);
    int p1 = atomicAdd(&cnt[i1], 1);
    tids[i0 * N_TOKENS + p0] = n;
    tids[i1 * N_TOKENS + p1] = n;
    meta[n] = make_int4(i0, p0, i1, p1);
    tw[n] = make_float2(p[i0] * inv, p[i1] * inv);
  }
}

// ------------------------------------------------------------- conversions ----
__global__ __launch_bounds__(256) void convx_kernel(const float* __restrict__ x,
                                                    short* __restrict__ xb) {
  int i = (blockIdx.x * 256 + threadIdx.x) * 4;
  float4 v = *(const float4*)(x + i);
  short4 o;
  o.x = (short)f2bf(v.x); o.y = (short)f2bf(v.y);
  o.z = (short)f2bf(v.z); o.w = (short)f2bf(v.w);
  *(short4*)(xb + i) = o;
}

// src [R][C] f32 (per expert slab), dst [C][R] bf16
__global__ __launch_bounds__(256) void transconv_kernel(
    const float* __restrict__ src, short* __restrict__ dst, int R, int C) {
  __shared__ float tile[64][65];
  int tx = threadIdx.x & 63, ty = threadIdx.x >> 6;
  size_t eoff = (size_t)blockIdx.z * R * C;
  int r0 = blockIdx.y * 64, c0 = blockIdx.x * 64;
  const float* s = src + eoff + (size_t)r0 * C + c0;
#pragma unroll
  for (int i = 0; i < 16; i++) {
    int r = i * 4 + ty;
    tile[r][tx] = s[(size_t)r * C + tx];
  }
  __syncthreads();
  short* d = dst + eoff + (size_t)c0 * R + r0;
#pragma unroll
  for (int i = 0; i < 16; i++) {
    int c = i * 4 + ty;
    d[(size_t)c * R + tx] = (short)f2bf(tile[tx][c]);
  }
}

// ------------------------------------------------------------------ GEMM1 ----
// H[off_e + t][:] = relu(x[tok] @ W1[e] + b1[e]),  A gathered by token list
// 2-phase double-buffered staging; source-swizzled LDS (T2 via m173); XCD swizzle.
__global__ __launch_bounds__(256) void gemm1_kernel(
    const short* __restrict__ xb,   // [2048][1024] bf16
    const short* __restrict__ W1b,  // [8][4096][1024] bf16 (n-major)
    const float* __restrict__ b1,   // [8][4096]
    const int* __restrict__ cnt, const int* __restrict__ tids,
    short* __restrict__ H) {        // [4096][4096] bf16 compact
  const int NT_M = N_TOKENS / 128, NT_N = D_HID / 128;
  // XCD-chunked swizzle: grid = 4096 (%8==0) -> each XCD gets one expert.
  int bid0 = blockIdx.x;
  int bid = (bid0 & 7) * ((NE * NT_M * NT_N) >> 3) + (bid0 >> 3);
  int e = bid / (NT_M * NT_N);
  int r2 = bid % (NT_M * NT_N);
  int mt = r2 % NT_M, nt = r2 / NT_M;
  int ce = cnt[e];
  if (mt * 128 >= ce) return;
  int off = 0;
  for (int i = 0; i < e; i++) off += cnt[i];

  __shared__ alignas(16) short As[2][128][64];
  __shared__ alignas(16) short Bs[2][128][64];

  int lane = threadIdx.x & 63, wid = threadIdx.x >> 6;
  int wr = wid >> 1, wc = wid & 1;
  int lrow = lane >> 3;
  int ach = ((lane & 7) ^ lrow) * 8;   // pre-swizzled source chunk (shorts)

  const int* tlist = tids + e * N_TOKENS + mt * 128;
  const short* agp[4];
  const short* bgp[4];
#pragma unroll
  for (int c = 0; c < 4; c++) {
    int r = c * 32 + wid * 8 + lrow;
    int t = (mt * 128 + r < ce) ? tlist[r] : tlist[0];
    agp[c] = xb + (size_t)t * D_IN + ach;
    bgp[c] = W1b + (size_t)e * D_HID * D_IN + (size_t)(nt * 128 + r) * D_IN + ach;
  }

  f32x4 zero = {0.f, 0.f, 0.f, 0.f};
  f32x4 acc[4][4];
#pragma unroll
  for (int i = 0; i < 4; i++) {
#pragma unroll
    for (int j = 0; j < 4; j++) acc[i][j] = zero;
  }

#define STAGE1(ks, buf)                                                         \
  {                                                                             \
    int k0 = (ks) * 64;                                                         \
    _Pragma("unroll")                                                           \
    for (int c = 0; c < 4; c++) {                                               \
      GLDS16(agp[c] + k0, &As[buf][c * 32 + wid * 8][0]);                       \
      GLDS16(bgp[c] + k0, &Bs[buf][c * 32 + wid * 8][0]);                       \
    }                                                                           \
  }

  const int NK = D_IN / 64;  // 16
  STAGE1(0, 0);
  __syncthreads();
  int cur = 0;
  for (int ks = 0; ks < NK; ks++) {
    if (ks + 1 < NK) STAGE1(ks + 1, cur ^ 1);
#pragma unroll
    for (int kk = 0; kk < 2; kk++) {
      s16x8 a[4], b[4];
      int ch = ((kk * 4 + (lane >> 4)) ^ (lane & 7)) * 8;  // swizzled read chunk
#pragma unroll
      for (int i = 0; i < 4; i++)
        a[i] = *(const s16x8*)&As[cur][wr * 64 + i * 16 + (lane & 15)][ch];
#pragma unroll
      for (int j = 0; j < 4; j++)
        b[j] = *(const s16x8*)&Bs[cur][wc * 64 + j * 16 + (lane & 15)][ch];
#pragma unroll
      for (int i = 0; i < 4; i++) {
#pragma unroll
        for (int j = 0; j < 4; j++)
          acc[i][j] = __builtin_amdgcn_mfma_f32_16x16x32_bf16(a[i], b[j], acc[i][j], 0, 0, 0);
      }
    }
    __syncthreads();
    cur ^= 1;
  }

  int lr = (lane >> 4) * 4, lc = lane & 15;
#pragma unroll
  for (int j = 0; j < 4; j++) {
    int col = nt * 128 + wc * 64 + j * 16 + lc;
    float bias = b1[e * D_HID + col];
#pragma unroll
    for (int i = 0; i < 4; i++) {
#pragma unroll
      for (int r = 0; r < 4; r++) {
        int grow = mt * 128 + wr * 64 + i * 16 + lr + r;
        if (grow < ce) {
          float v = fmaxf(acc[i][j][r] + bias, 0.f);
          H[(size_t)(off + grow) * D_HID + col] = (short)f2bf(v);
        }
      }
    }
  }
}

// ------------------------------------------------------------------ GEMM2 ----
// Y[off_e + t][:] = H[off_e + t] @ W2[e]    (f32 out, bias folded into combine)
__global__ __launch_bounds__(256) void gemm2_kernel(
    const short* __restrict__ H,    // [4096][4096] bf16
    const short* __restrict__ W2b,  // [8][1024][4096] bf16 (n-major)
    const int* __restrict__ cnt,
    float* __restrict__ Y) {        // [4096][1024] f32
  const int NT_M = N_TOKENS / 128, NT_N = D_OUT / 128;
  int bid0 = blockIdx.x;
  int bid = (bid0 & 7) * ((NE * NT_M * NT_N) >> 3) + (bid0 >> 3);
  int e = bid / (NT_M * NT_N);
  int r2 = bid % (NT_M * NT_N);
  int mt = r2 % NT_M, nt = r2 / NT_M;
  int ce = cnt[e];
  if (mt * 128 >= ce) return;
  int off = 0;
  for (int i = 0; i < e; i++) off += cnt[i];

  __shared__ alignas(16) short As[2][128][64];
  __shared__ alignas(16) short Bs[2][128][64];

  int lane = threadIdx.x & 63, wid = threadIdx.x >> 6;
  int wr = wid >> 1, wc = wid & 1;
  int lrow = lane >> 3;
  int ach = ((lane & 7) ^ lrow) * 8;

  const short* agp[4];
  const short* bgp[4];
#pragma unroll
  for (int c = 0; c < 4; c++) {
    int r = c * 32 + wid * 8 + lrow;
    int grow = mt * 128 + r;
    if (grow > ce - 1) grow = ce - 1;
    agp[c] = H + (size_t)(off + grow) * D_HID + ach;
    bgp[c] = W2b + (size_t)e * D_OUT * D_HID + (size_t)(nt * 128 + r) * D_HID + ach;
  }

  f32x4 zero = {0.f, 0.f, 0.f, 0.f};
  f32x4 acc[4][4];
#pragma unroll
  for (int i = 0; i < 4; i++) {
#pragma unroll
    for (int j = 0; j < 4; j++) acc[i][j] = zero;
  }

#define STAGE2(ks, buf)                                                         \
  {                                                                             \
    int k0 = (ks) * 64;                                                         \
    _Pragma("unroll")                                                           \
    for (int c = 0; c < 4; c++) {                                               \
      GLDS16(agp[c] + k0, &As[buf][c * 32 + wid * 8][0]);                       \
      GLDS16(bgp[c] + k0, &Bs[buf][c * 32 + wid * 8][0]);                       \
    }                                                                           \
  }

  const int NK = D_HID / 64;  // 64
  STAGE2(0, 0);
  __syncthreads();
  int cur = 0;
  for (int ks = 0; ks < NK; ks++) {
    if (ks + 1 < NK) STAGE2(ks + 1, cur ^ 1);
#pragma unroll
    for (int kk = 0; kk < 2; kk++) {
      s16x8 a[4], b[4];
      int ch = ((kk * 4 + (lane >> 4)) ^ (lane & 7)) * 8;
#pragma unroll
      for (int i = 0; i < 4; i++)
        a[i] = *(const s16x8*)&As[cur][wr * 64 + i * 16 + (lane & 15)][ch];
#pragma unroll
      for (int j = 0; j < 4; j++)
        b[j] = *(const s16x8*)&Bs[cur][wc * 64 + j * 16 + (lane & 15)][ch];
#pragma unroll
      for (int i = 0; i < 4; i++) {
#pragma unroll
        for (int j = 0; j < 4; j++)
          acc[i][j] = __builtin_amdgcn_mfma_f32_16x16x32_bf16(a[i], b[j], acc[i][j], 0, 0, 0);
      }
    }
    __syncthreads();
    cur ^= 1;
  }

  int lr = (lane >> 4) * 4, lc = lane & 15;
#pragma unroll
  for (int j = 0; j < 4; j++) {
    int col = nt * 128 + wc * 64 + j * 16 + lc;
#pragma unroll
    for (int i = 0; i < 4; i++) {
#pragma unroll
      for (int r = 0; r < 4; r++) {
        int grow = mt * 128 + wr * 64 + i * 16 + lr + r;
        if (grow < ce) Y[(size_t)(off + grow) * D_OUT + col] = acc[i][j][r];
      }
    }
  }
}

// ---------------------------------------------------------------- combine ----
__global__ __launch_bounds__(256) void combine_kernel(
    const float* __restrict__ Y, const float* __restrict__ b2,
    const int* __restrict__ cnt, const int4* __restrict__ meta,
    const float2* __restrict__ tw, float* __restrict__ out) {
  int n = blockIdx.x;
  int4 m = meta[n];
  float2 w = tw[n];
  int off0 = 0, off1 = 0;
#pragma unroll
  for (int i = 0; i < NE; i++) {
    int c = cnt[i];
    if (i < m.x) off0 += c;
    if (i < m.z) off1 += c;
  }
  const float4* y0 = (const float4*)(Y + (size_t)(off0 + m.y) * D_OUT);
  const float4* y1 = (const float4*)(Y + (size_t)(off1 + m.w) * D_OUT);
  const float4* g0 = (const float4*)(b2 + (size_t)m.x * D_OUT);
  const float4* g1 = (const float4*)(b2 + (size_t)m.z * D_OUT);
  float4* o = (float4*)(out + (size_t)n * D_OUT);
  int d = threadIdx.x;  // 256 threads x float4 = 1024 floats
  float4 a = y0[d], b = y1[d], ba = g0[d], bb = g1[d];
  float4 r;
  r.x = w.x * (a.x + ba.x) + w.y * (b.x + bb.x);
  r.y = w.x * (a.y + ba.y) + w.y * (b.y + bb.y);
  r.z = w.x * (a.z + ba.z) + w.y * (b.z + bb.z);
  r.w = w.x * (a.w + ba.w) + w.y * (b.w + bb.w);
  o[d] = r;
}

// ----------------------------------------------------------------- launch ----
extern "C" void kernel_launch(void* const* d_in, const int* in_sizes, int n_in,
                              void* d_out, int out_size, void* d_ws, size_t ws_size,
                              hipStream_t stream) {
  const float* x  = (const float*)d_in[0];
  const float* Wr = (const float*)d_in[1];
  const float* br = (const float*)d_in[2];
  const float* W1 = (const float*)d_in[3];
  const float* b1 = (const float*)d_in[4];
  const float* W2 = (const float*)d_in[5];
  const float* b2 = (const float*)d_in[6];
  float* out = (float*)d_out;

  char* ws = (char*)d_ws;
  size_t o = 0;
  auto alloc = [&](size_t bytes) -> void* {
    o = (o + 255) & ~(size_t)255;
    void* p = ws + o;
    o += bytes;
    return p;
  };
  int*    cnt  = (int*)alloc(NE * 4);
  int*    tids = (int*)alloc((size_t)NE * N_TOKENS * 4);
  int4*   meta = (int4*)alloc((size_t)N_TOKENS * 16);
  float2* tw   = (float2*)alloc((size_t)N_TOKENS * 8);
  short*  xb   = (short*)alloc((size_t)N_TOKENS * D_IN * 2);
  short*  W1b  = (short*)alloc((size_t)NE * D_HID * D_IN * 2);
  short*  W2b  = (short*)alloc((size_t)NE * D_OUT * D_HID * 2);
  short*  H    = (short*)alloc((size_t)2 * N_TOKENS * D_HID * 2);
  float*  Y    = (float*)alloc((size_t)2 * N_TOKENS * D_OUT * 4);
  if (o > ws_size) return;  // workspace too small; fail loudly via wrong output

  hipMemsetAsync(cnt, 0, NE * 4, stream);
  router_kernel<<<N_TOKENS / 4, 256, 0, stream>>>(x, Wr, br, cnt, tids, meta, tw);
  convx_kernel<<<(N_TOKENS * D_IN / 4) / 256, 256, 0, stream>>>(x, xb);
  transconv_kernel<<<dim3(D_HID / 64, D_IN / 64, NE), 256, 0, stream>>>(W1, W1b, D_IN, D_HID);
  transconv_kernel<<<dim3(D_OUT / 64, D_HID / 64, NE), 256, 0, stream>>>(W2, W2b, D_HID, D_OUT);
  gemm1_kernel<<<NE * (N_TOKENS / 128) * (D_HID / 128), 256, 0, stream>>>(xb, W1b, b1, cnt, tids, H);
  gemm2_kernel<<<NE * (N_TOKENS / 128) * (D_OUT / 128), 256, 0, stream>>>(H, W2b, cnt, Y);
  combine_kernel<<<N_TOKENS, 256, 0, stream>>>(Y, b2, cnt, meta, tw, out);
}

// Round 7
// 579.163 us; speedup vs baseline: 1.4581x; 1.0372x over previous
//
#include <hip/hip_runtime.h>
#include <hip/hip_bf16.h>

#define N_TOKENS 2048
#define D_IN 1024
#define D_HID 4096
#define D_OUT 1024
#define NE 8

typedef __attribute__((ext_vector_type(8))) short s16x8;
typedef __attribute__((ext_vector_type(4))) float f32x4;

__device__ inline unsigned short f2bf(float f) {
  union { float f; unsigned u; } v; v.f = f;
  unsigned u = v.u;
  unsigned r = u + 0x7fff + ((u >> 16) & 1);   // round-to-nearest-even
  return (unsigned short)(r >> 16);
}

#define GLDS16(gp, lp)                                                          \
  __builtin_amdgcn_global_load_lds(                                             \
      (const __attribute__((address_space(1))) unsigned int*)(gp),              \
      (__attribute__((address_space(3))) unsigned int*)(lp), 16, 0, 0)

// ---------------------------------------------------------------- router ----
__global__ __launch_bounds__(256) void router_kernel(
    const float* __restrict__ x, const float* __restrict__ Wr,
    const float* __restrict__ br, int* __restrict__ cnt, int* __restrict__ tids,
    int4* __restrict__ meta, float2* __restrict__ tw) {
  int wid = threadIdx.x >> 6, lane = threadIdx.x & 63;
  int n = blockIdx.x * 4 + wid;
  const float* xr = x + (size_t)n * D_IN;
  float acc[NE];
#pragma unroll
  for (int e = 0; e < NE; e++) acc[e] = 0.f;
  for (int i = lane; i < D_IN; i += 64) {
    float xv = xr[i];
    const float4* wr = (const float4*)(Wr + (size_t)i * NE);
    float4 w0 = wr[0], w1 = wr[1];
    acc[0] += xv * w0.x; acc[1] += xv * w0.y;
    acc[2] += xv * w0.z; acc[3] += xv * w0.w;
    acc[4] += xv * w1.x; acc[5] += xv * w1.y;
    acc[6] += xv * w1.z; acc[7] += xv * w1.w;
  }
#pragma unroll
  for (int e = 0; e < NE; e++) {
#pragma unroll
    for (int s = 32; s; s >>= 1) acc[e] += __shfl_xor(acc[e], s, 64);
  }
  if (lane == 0) {
    float lg[NE], p[NE];
    float m = -1e30f;
#pragma unroll
    for (int e = 0; e < NE; e++) { lg[e] = acc[e] + br[e]; m = fmaxf(m, lg[e]); }
    float s = 0.f;
#pragma unroll
    for (int e = 0; e < NE; e++) { p[e] = expf(lg[e] - m); s += p[e]; }
    float inv = 1.f / s;
    int i0 = 0;
#pragma unroll
    for (int e = 1; e < NE; e++) if (lg[e] > lg[i0]) i0 = e;
    int i1 = (i0 == 0) ? 1 : 0;
#pragma unroll
    for (int e = 0; e < NE; e++) if (e != i0 && lg[e] > lg[i1]) i1 = e;
    int p0 = atomicAdd(&cnt[i0], 1);
    int p1 = atomicAdd(&cnt[i1], 1);
    tids[i0 * N_TOKENS + p0] = n;
    tids[i1 * N_TOKENS + p1] = n;
    meta[n] = make_int4(i0, p0, i1, p1);
    tw[n] = make_float2(p[i0] * inv, p[i1] * inv);
  }
}

// ------------------------------------------------------------- conversions ----
__global__ __launch_bounds__(256) void convx_kernel(const float* __restrict__ x,
                                                    short* __restrict__ xb) {
  int i = (blockIdx.x * 256 + threadIdx.x) * 4;
  float4 v = *(const float4*)(x + i);
  short4 o;
  o.x = (short)f2bf(v.x); o.y = (short)f2bf(v.y);
  o.z = (short)f2bf(v.z); o.w = (short)f2bf(v.w);
  *(short4*)(xb + i) = o;
}

// src [R][C] f32 (per expert slab), dst [C][R] bf16. float4 loads, short4 writes.
__global__ __launch_bounds__(256) void transconv_kernel(
    const float* __restrict__ src, short* __restrict__ dst, int R, int C) {
  __shared__ float tile[64][65];
  size_t eoff = (size_t)blockIdx.z * R * C;
  int r0 = blockIdx.y * 64, c0 = blockIdx.x * 64;
  const float* s = src + eoff + (size_t)r0 * C + c0;
  int t = threadIdx.x;
  int lc4 = (t & 15) * 4;   // col group of 4
  int lr16 = t >> 4;        // 16 rows per pass
#pragma unroll
  for (int p = 0; p < 4; p++) {
    int r = p * 16 + lr16;
    float4 v = *(const float4*)(s + (size_t)r * C + lc4);
    tile[r][lc4 + 0] = v.x; tile[r][lc4 + 1] = v.y;
    tile[r][lc4 + 2] = v.z; tile[r][lc4 + 3] = v.w;
  }
  __syncthreads();
  short* d = dst + eoff + (size_t)c0 * R + r0;
  int rr4 = (t & 15) * 4;   // row group of 4 (contiguous along R in dst)
  int cc = t >> 4;          // 16 cols per pass
#pragma unroll
  for (int p = 0; p < 4; p++) {
    int c = p * 16 + cc;
    short4 o;
    o.x = (short)f2bf(tile[rr4 + 0][c]);
    o.y = (short)f2bf(tile[rr4 + 1][c]);
    o.z = (short)f2bf(tile[rr4 + 2][c]);
    o.w = (short)f2bf(tile[rr4 + 3][c]);
    *(short4*)(d + (size_t)c * R + rr4) = o;
  }
}

// ------------------------------------------------------------------ GEMM1 ----
// H[off_e + t][:] = relu(x[tok] @ W1[e] + b1[e]),  A gathered by token list.
// 2-buffer pipeline with counted vmcnt (T4): prefetch stays in flight across
// raw s_barriers; vmcnt(8) waits only the current tile's 8 global_load_lds.
__global__ __launch_bounds__(256) void gemm1_kernel(
    const short* __restrict__ xb,   // [2048][1024] bf16
    const short* __restrict__ W1b,  // [8][4096][1024] bf16 (n-major)
    const float* __restrict__ b1,   // [8][4096]
    const int* __restrict__ cnt, const int* __restrict__ tids,
    short* __restrict__ H) {        // [4096][4096] bf16 compact
  const int NT_M = N_TOKENS / 128, NT_N = D_HID / 128;
  int bid0 = blockIdx.x;
  int bid = (bid0 & 7) * ((NE * NT_M * NT_N) >> 3) + (bid0 >> 3);
  int e = bid / (NT_M * NT_N);
  int r2 = bid % (NT_M * NT_N);
  int mt = r2 % NT_M, nt = r2 / NT_M;
  int ce = cnt[e];
  if (mt * 128 >= ce) return;
  int off = 0;
  for (int i = 0; i < e; i++) off += cnt[i];

  __shared__ alignas(16) short As[2][128][64];
  __shared__ alignas(16) short Bs[2][128][64];

  int lane = threadIdx.x & 63, wid = threadIdx.x >> 6;
  int wr = wid >> 1, wc = wid & 1;
  int lrow = lane >> 3;
  int ach = ((lane & 7) ^ lrow) * 8;   // pre-swizzled source chunk (shorts)

  const int* tlist = tids + e * N_TOKENS + mt * 128;
  const short* agp[4];
  const short* bgp[4];
#pragma unroll
  for (int c = 0; c < 4; c++) {
    int r = c * 32 + wid * 8 + lrow;
    int t = (mt * 128 + r < ce) ? tlist[r] : tlist[0];
    agp[c] = xb + (size_t)t * D_IN + ach;
    bgp[c] = W1b + (size_t)e * D_HID * D_IN + (size_t)(nt * 128 + r) * D_IN + ach;
  }

  f32x4 zero = {0.f, 0.f, 0.f, 0.f};
  f32x4 acc[4][4];
#pragma unroll
  for (int i = 0; i < 4; i++) {
#pragma unroll
    for (int j = 0; j < 4; j++) acc[i][j] = zero;
  }

#define STAGE1(ks, buf)                                                         \
  {                                                                             \
    int k0 = (ks) * 64;                                                         \
    _Pragma("unroll")                                                           \
    for (int c = 0; c < 4; c++) {                                               \
      GLDS16(agp[c] + k0, &As[buf][c * 32 + wid * 8][0]);                       \
      GLDS16(bgp[c] + k0, &Bs[buf][c * 32 + wid * 8][0]);                       \
    }                                                                           \
  }

  const int NK = D_IN / 64;  // 16
  STAGE1(0, 0);
  STAGE1(1, 1);
  int cur = 0;
  for (int ks = 0; ks < NK; ks++) {
    // wait: tile ks landed (its 8 loads are the oldest); newer 8 stay in flight
    if (ks + 1 < NK) asm volatile("s_waitcnt vmcnt(8)" : : : "memory");
    else             asm volatile("s_waitcnt vmcnt(0)" : : : "memory");
    __builtin_amdgcn_s_barrier();
#pragma unroll
    for (int kk = 0; kk < 2; kk++) {
      s16x8 a[4], b[4];
      int ch = ((kk * 4 + (lane >> 4)) ^ (lane & 7)) * 8;  // swizzled read chunk
#pragma unroll
      for (int i = 0; i < 4; i++)
        a[i] = *(const s16x8*)&As[cur][wr * 64 + i * 16 + (lane & 15)][ch];
#pragma unroll
      for (int j = 0; j < 4; j++)
        b[j] = *(const s16x8*)&Bs[cur][wc * 64 + j * 16 + (lane & 15)][ch];
#pragma unroll
      for (int i = 0; i < 4; i++) {
#pragma unroll
        for (int j = 0; j < 4; j++)
          acc[i][j] = __builtin_amdgcn_mfma_f32_16x16x32_bf16(a[i], b[j], acc[i][j], 0, 0, 0);
      }
    }
    __builtin_amdgcn_s_barrier();   // all waves done reading buf[cur]
    if (ks + 2 < NK) STAGE1(ks + 2, cur);
    cur ^= 1;
  }

  int lr = (lane >> 4) * 4, lc = lane & 15;
#pragma unroll
  for (int j = 0; j < 4; j++) {
    int col = nt * 128 + wc * 64 + j * 16 + lc;
    float bias = b1[e * D_HID + col];
#pragma unroll
    for (int i = 0; i < 4; i++) {
#pragma unroll
      for (int r = 0; r < 4; r++) {
        int grow = mt * 128 + wr * 64 + i * 16 + lr + r;
        if (grow < ce) {
          float v = fmaxf(acc[i][j][r] + bias, 0.f);
          H[(size_t)(off + grow) * D_HID + col] = (short)f2bf(v);
        }
      }
    }
  }
}

// ------------------------------------------------------------------ GEMM2 ----
// Y[off_e + t][:] = H[off_e + t] @ W2[e]    (f32 out, bias folded into combine)
__global__ __launch_bounds__(256) void gemm2_kernel(
    const short* __restrict__ H,    // [4096][4096] bf16
    const short* __restrict__ W2b,  // [8][1024][4096] bf16 (n-major)
    const int* __restrict__ cnt,
    float* __restrict__ Y) {        // [4096][1024] f32
  const int NT_M = N_TOKENS / 128, NT_N = D_OUT / 128;
  int bid0 = blockIdx.x;
  int bid = (bid0 & 7) * ((NE * NT_M * NT_N) >> 3) + (bid0 >> 3);
  int e = bid / (NT_M * NT_N);
  int r2 = bid % (NT_M * NT_N);
  int mt = r2 % NT_M, nt = r2 / NT_M;
  int ce = cnt[e];
  if (mt * 128 >= ce) return;
  int off = 0;
  for (int i = 0; i < e; i++) off += cnt[i];

  __shared__ alignas(16) short As[2][128][64];
  __shared__ alignas(16) short Bs[2][128][64];

  int lane = threadIdx.x & 63, wid = threadIdx.x >> 6;
  int wr = wid >> 1, wc = wid & 1;
  int lrow = lane >> 3;
  int ach = ((lane & 7) ^ lrow) * 8;

  const short* agp[4];
  const short* bgp[4];
#pragma unroll
  for (int c = 0; c < 4; c++) {
    int r = c * 32 + wid * 8 + lrow;
    int grow = mt * 128 + r;
    if (grow > ce - 1) grow = ce - 1;
    agp[c] = H + (size_t)(off + grow) * D_HID + ach;
    bgp[c] = W2b + (size_t)e * D_OUT * D_HID + (size_t)(nt * 128 + r) * D_HID + ach;
  }

  f32x4 zero = {0.f, 0.f, 0.f, 0.f};
  f32x4 acc[4][4];
#pragma unroll
  for (int i = 0; i < 4; i++) {
#pragma unroll
    for (int j = 0; j < 4; j++) acc[i][j] = zero;
  }

#define STAGE2(ks, buf)                                                         \
  {                                                                             \
    int k0 = (ks) * 64;                                                         \
    _Pragma("unroll")                                                           \
    for (int c = 0; c < 4; c++) {                                               \
      GLDS16(agp[c] + k0, &As[buf][c * 32 + wid * 8][0]);                       \
      GLDS16(bgp[c] + k0, &Bs[buf][c * 32 + wid * 8][0]);                       \
    }                                                                           \
  }

  const int NK = D_HID / 64;  // 64
  STAGE2(0, 0);
  STAGE2(1, 1);
  int cur = 0;
  for (int ks = 0; ks < NK; ks++) {
    if (ks + 1 < NK) asm volatile("s_waitcnt vmcnt(8)" : : : "memory");
    else             asm volatile("s_waitcnt vmcnt(0)" : : : "memory");
    __builtin_amdgcn_s_barrier();
#pragma unroll
    for (int kk = 0; kk < 2; kk++) {
      s16x8 a[4], b[4];
      int ch = ((kk * 4 + (lane >> 4)) ^ (lane & 7)) * 8;
#pragma unroll
      for (int i = 0; i < 4; i++)
        a[i] = *(const s16x8*)&As[cur][wr * 64 + i * 16 + (lane & 15)][ch];
#pragma unroll
      for (int j = 0; j < 4; j++)
        b[j] = *(const s16x8*)&Bs[cur][wc * 64 + j * 16 + (lane & 15)][ch];
#pragma unroll
      for (int i = 0; i < 4; i++) {
#pragma unroll
        for (int j = 0; j < 4; j++)
          acc[i][j] = __builtin_amdgcn_mfma_f32_16x16x32_bf16(a[i], b[j], acc[i][j], 0, 0, 0);
      }
    }
    __builtin_amdgcn_s_barrier();
    if (ks + 2 < NK) STAGE2(ks + 2, cur);
    cur ^= 1;
  }

  int lr = (lane >> 4) * 4, lc = lane & 15;
#pragma unroll
  for (int j = 0; j < 4; j++) {
    int col = nt * 128 + wc * 64 + j * 16 + lc;
#pragma unroll
    for (int i = 0; i < 4; i++) {
#pragma unroll
      for (int r = 0; r < 4; r++) {
        int grow = mt * 128 + wr * 64 + i * 16 + lr + r;
        if (grow < ce) Y[(size_t)(off + grow) * D_OUT + col] = acc[i][j][r];
      }
    }
  }
}

// ---------------------------------------------------------------- combine ----
__global__ __launch_bounds__(256) void combine_kernel(
    const float* __restrict__ Y, const float* __restrict__ b2,
    const int* __restrict__ cnt, const int4* __restrict__ meta,
    const float2* __restrict__ tw, float* __restrict__ out) {
  int n = blockIdx.x;
  int4 m = meta[n];
  float2 w = tw[n];
  int off0 = 0, off1 = 0;
#pragma unroll
  for (int i = 0; i < NE; i++) {
    int c = cnt[i];
    if (i < m.x) off0 += c;
    if (i < m.z) off1 += c;
  }
  const float4* y0 = (const float4*)(Y + (size_t)(off0 + m.y) * D_OUT);
  const float4* y1 = (const float4*)(Y + (size_t)(off1 + m.w) * D_OUT);
  const float4* g0 = (const float4*)(b2 + (size_t)m.x * D_OUT);
  const float4* g1 = (const float4*)(b2 + (size_t)m.z * D_OUT);
  float4* o = (float4*)(out + (size_t)n * D_OUT);
  int d = threadIdx.x;  // 256 threads x float4 = 1024 floats
  float4 a = y0[d], b = y1[d], ba = g0[d], bb = g1[d];
  float4 r;
  r.x = w.x * (a.x + ba.x) + w.y * (b.x + bb.x);
  r.y = w.x * (a.y + ba.y) + w.y * (b.y + bb.y);
  r.z = w.x * (a.z + ba.z) + w.y * (b.z + bb.z);
  r.w = w.x * (a.w + ba.w) + w.y * (b.w + bb.w);
  o[d] = r;
}

// ----------------------------------------------------------------- launch ----
extern "C" void kernel_launch(void* const* d_in, const int* in_sizes, int n_in,
                              void* d_out, int out_size, void* d_ws, size_t ws_size,
                              hipStream_t stream) {
  const float* x  = (const float*)d_in[0];
  const float* Wr = (const float*)d_in[1];
  const float* br = (const float*)d_in[2];
  const float* W1 = (const float*)d_in[3];
  const float* b1 = (const float*)d_in[4];
  const float* W2 = (const float*)d_in[5];
  const float* b2 = (const float*)d_in[6];
  float* out = (float*)d_out;

  char* ws = (char*)d_ws;
  size_t o = 0;
  auto alloc = [&](size_t bytes) -> void* {
    o = (o + 255) & ~(size_t)255;
    void* p = ws + o;
    o += bytes;
    return p;
  };
  int*    cnt  = (int*)alloc(NE * 4);
  int*    tids = (int*)alloc((size_t)NE * N_TOKENS * 4);
  int4*   meta = (int4*)alloc((size_t)N_TOKENS * 16);
  float2* tw   = (float2*)alloc((size_t)N_TOKENS * 8);
  short*  xb   = (short*)alloc((size_t)N_TOKENS * D_IN * 2);
  short*  W1b  = (short*)alloc((size_t)NE * D_HID * D_IN * 2);
  short*  W2b  = (short*)alloc((size_t)NE * D_OUT * D_HID * 2);
  short*  H    = (short*)alloc((size_t)2 * N_TOKENS * D_HID * 2);
  float*  Y    = (float*)alloc((size_t)2 * N_TOKENS * D_OUT * 4);
  if (o > ws_size) return;  // workspace too small; fail loudly via wrong output

  hipMemsetAsync(cnt, 0, NE * 4, stream);
  router_kernel<<<N_TOKENS / 4, 256, 0, stream>>>(x, Wr, br, cnt, tids, meta, tw);
  convx_kernel<<<(N_TOKENS * D_IN / 4) / 256, 256, 0, stream>>>(x, xb);
  transconv_kernel<<<dim3(D_HID / 64, D_IN / 64, NE), 256, 0, stream>>>(W1, W1b, D_IN, D_HID);
  transconv_kernel<<<dim3(D_OUT / 64, D_HID / 64, NE), 256, 0, stream>>>(W2, W2b, D_HID, D_OUT);
  gemm1_kernel<<<NE * (N_TOKENS / 128) * (D_HID / 128), 256, 0, stream>>>(xb, W1b, b1, cnt, tids, H);
  gemm2_kernel<<<NE * (N_TOKENS / 128) * (D_OUT / 128), 256, 0, stream>>>(H, W2b, cnt, Y);
  combine_kernel<<<N_TOKENS, 256, 0, stream>>>(Y, b2, cnt, meta, tw, out);
}

// Round 8
// 564.199 us; speedup vs baseline: 1.4968x; 1.0265x over previous
//
#include <hip/hip_runtime.h>
#include <hip/hip_bf16.h>

#define N_TOKENS 2048
#define D_IN 1024
#define D_HID 4096
#define D_OUT 1024
#define NE 8

typedef __attribute__((ext_vector_type(8))) short s16x8;
typedef __attribute__((ext_vector_type(4))) float f32x4;

__device__ inline unsigned short f2bf(float f) {
  union { float f; unsigned u; } v; v.f = f;
  unsigned u = v.u;
  unsigned r = u + 0x7fff + ((u >> 16) & 1);   // round-to-nearest-even
  return (unsigned short)(r >> 16);
}

#define GLDS16(gp, lp)                                                          \
  __builtin_amdgcn_global_load_lds(                                             \
      (const __attribute__((address_space(1))) unsigned int*)(gp),              \
      (__attribute__((address_space(3))) unsigned int*)(lp), 16, 0, 0)

// ---------------------------------------------------------------- router ----
__global__ __launch_bounds__(256) void router_kernel(
    const float* __restrict__ x, const float* __restrict__ Wr,
    const float* __restrict__ br, int* __restrict__ cnt, int* __restrict__ tids,
    int4* __restrict__ meta, float2* __restrict__ tw) {
  int wid = threadIdx.x >> 6, lane = threadIdx.x & 63;
  int n = blockIdx.x * 4 + wid;
  const float* xr = x + (size_t)n * D_IN;
  float acc[NE];
#pragma unroll
  for (int e = 0; e < NE; e++) acc[e] = 0.f;
  for (int i = lane; i < D_IN; i += 64) {
    float xv = xr[i];
    const float4* wr = (const float4*)(Wr + (size_t)i * NE);
    float4 w0 = wr[0], w1 = wr[1];
    acc[0] += xv * w0.x; acc[1] += xv * w0.y;
    acc[2] += xv * w0.z; acc[3] += xv * w0.w;
    acc[4] += xv * w1.x; acc[5] += xv * w1.y;
    acc[6] += xv * w1.z; acc[7] += xv * w1.w;
  }
#pragma unroll
  for (int e = 0; e < NE; e++) {
#pragma unroll
    for (int s = 32; s; s >>= 1) acc[e] += __shfl_xor(acc[e], s, 64);
  }
  if (lane == 0) {
    float lg[NE], p[NE];
    float m = -1e30f;
#pragma unroll
    for (int e = 0; e < NE; e++) { lg[e] = acc[e] + br[e]; m = fmaxf(m, lg[e]); }
    float s = 0.f;
#pragma unroll
    for (int e = 0; e < NE; e++) { p[e] = expf(lg[e] - m); s += p[e]; }
    float inv = 1.f / s;
    int i0 = 0;
#pragma unroll
    for (int e = 1; e < NE; e++) if (lg[e] > lg[i0]) i0 = e;
    int i1 = (i0 == 0) ? 1 : 0;
#pragma unroll
    for (int e = 0; e < NE; e++) if (e != i0 && lg[e] > lg[i1]) i1 = e;
    int p0 = atomicAdd(&cnt[i0], 1);
    int p1 = atomicAdd(&cnt[i1], 1);
    tids[i0 * N_TOKENS + p0] = n;
    tids[i1 * N_TOKENS + p1] = n;
    meta[n] = make_int4(i0, p0, i1, p1);
    tw[n] = make_float2(p[i0] * inv, p[i1] * inv);
  }
}

// ------------------------------------------------------------- conversions ----
__global__ __launch_bounds__(256) void convx_kernel(const float* __restrict__ x,
                                                    short* __restrict__ xb) {
  int i = (blockIdx.x * 256 + threadIdx.x) * 4;
  float4 v = *(const float4*)(x + i);
  short4 o;
  o.x = (short)f2bf(v.x); o.y = (short)f2bf(v.y);
  o.z = (short)f2bf(v.z); o.w = (short)f2bf(v.w);
  *(short4*)(xb + i) = o;
}

// src [R][C] f32 (per expert slab), dst [C][R] bf16. float4 loads, short4 writes.
__global__ __launch_bounds__(256) void transconv_kernel(
    const float* __restrict__ src, short* __restrict__ dst, int R, int C) {
  __shared__ float tile[64][65];
  size_t eoff = (size_t)blockIdx.z * R * C;
  int r0 = blockIdx.y * 64, c0 = blockIdx.x * 64;
  const float* s = src + eoff + (size_t)r0 * C + c0;
  int t = threadIdx.x;
  int lc4 = (t & 15) * 4;
  int lr16 = t >> 4;
#pragma unroll
  for (int p = 0; p < 4; p++) {
    int r = p * 16 + lr16;
    float4 v = *(const float4*)(s + (size_t)r * C + lc4);
    tile[r][lc4 + 0] = v.x; tile[r][lc4 + 1] = v.y;
    tile[r][lc4 + 2] = v.z; tile[r][lc4 + 3] = v.w;
  }
  __syncthreads();
  short* d = dst + eoff + (size_t)c0 * R + r0;
  int rr4 = (t & 15) * 4;
  int cc = t >> 4;
#pragma unroll
  for (int p = 0; p < 4; p++) {
    int c = p * 16 + cc;
    short4 o;
    o.x = (short)f2bf(tile[rr4 + 0][c]);
    o.y = (short)f2bf(tile[rr4 + 1][c]);
    o.z = (short)f2bf(tile[rr4 + 2][c]);
    o.w = (short)f2bf(tile[rr4 + 3][c]);
    *(short4*)(d + (size_t)c * R + rr4) = o;
  }
}

// ------------------------------------------------------------------ GEMM1 ----
// BK=32, 2 buffers (32 KiB LDS -> ~5 blocks/CU), counted vmcnt(4).
// LDS row = 64B = 4x16B chunks; slot ch holds global chunk ch^((row>>1)&3).
__global__ __launch_bounds__(256) void gemm1_kernel(
    const short* __restrict__ xb,   // [2048][1024] bf16
    const short* __restrict__ W1b,  // [8][4096][1024] bf16 (n-major)
    const float* __restrict__ b1,   // [8][4096]
    const int* __restrict__ cnt, const int* __restrict__ tids,
    short* __restrict__ H) {        // [4096][4096] bf16 compact
  const int NT_M = N_TOKENS / 128, NT_N = D_HID / 128;
  int bid0 = blockIdx.x;
  int bid = (bid0 & 7) * ((NE * NT_M * NT_N) >> 3) + (bid0 >> 3);
  int e = bid / (NT_M * NT_N);
  int r2 = bid % (NT_M * NT_N);
  int mt = r2 % NT_M, nt = r2 / NT_M;
  int ce = cnt[e];
  if (mt * 128 >= ce) return;
  int off = 0;
  for (int i = 0; i < e; i++) off += cnt[i];

  __shared__ alignas(16) short As[2][128][32];
  __shared__ alignas(16) short Bs[2][128][32];

  int lane = threadIdx.x & 63, wid = threadIdx.x >> 6;
  int wr = wid >> 1, wc = wid & 1;
  // staging: instr j of wave covers rows 16*(wid+4j)..+15; lane l -> row +(l>>2), slot l&3
  int srow = lane >> 2;
  int gch = ((lane & 3) ^ ((lane >> 3) & 3)) * 8;  // pre-swizzled global chunk (shorts)

  const int* tlist = tids + e * N_TOKENS + mt * 128;
  const short* a_src[2];
  const short* b_src[2];
#pragma unroll
  for (int j = 0; j < 2; j++) {
    int r = (wid + 4 * j) * 16 + srow;
    int t = (mt * 128 + r < ce) ? tlist[r] : tlist[0];
    a_src[j] = xb + (size_t)t * D_IN + gch;
    b_src[j] = W1b + (size_t)e * D_HID * D_IN + (size_t)(nt * 128 + r) * D_IN + gch;
  }

  f32x4 zero = {0.f, 0.f, 0.f, 0.f};
  f32x4 acc[4][4];
#pragma unroll
  for (int i = 0; i < 4; i++)
#pragma unroll
    for (int j = 0; j < 4; j++) acc[i][j] = zero;

#define STAGE1(ks, buf)                                                         \
  {                                                                             \
    int k0 = (ks) * 32;                                                         \
    GLDS16(a_src[0] + k0, &As[buf][wid * 16][0]);                               \
    GLDS16(a_src[1] + k0, &As[buf][(wid + 4) * 16][0]);                         \
    GLDS16(b_src[0] + k0, &Bs[buf][wid * 16][0]);                               \
    GLDS16(b_src[1] + k0, &Bs[buf][(wid + 4) * 16][0]);                         \
  }

  const int NK = D_IN / 32;  // 32
  STAGE1(0, 0);
  STAGE1(1, 1);
  int cur = 0;
  int chsh = (((lane >> 4) ^ ((lane >> 1) & 3)) & 3) * 8;  // read slot (shorts)
  int arow = wr * 64 + (lane & 15), brow = wc * 64 + (lane & 15);
  for (int ks = 0; ks < NK; ks++) {
    if (ks + 1 < NK) asm volatile("s_waitcnt vmcnt(4)" : : : "memory");
    else             asm volatile("s_waitcnt vmcnt(0)" : : : "memory");
    __builtin_amdgcn_s_barrier();
    s16x8 a[4], b[4];
#pragma unroll
    for (int i = 0; i < 4; i++)
      a[i] = *(const s16x8*)&As[cur][arow + i * 16][chsh];
#pragma unroll
    for (int j = 0; j < 4; j++)
      b[j] = *(const s16x8*)&Bs[cur][brow + j * 16][chsh];
#pragma unroll
    for (int i = 0; i < 4; i++)
#pragma unroll
      for (int j = 0; j < 4; j++)
        acc[i][j] = __builtin_amdgcn_mfma_f32_16x16x32_bf16(a[i], b[j], acc[i][j], 0, 0, 0);
    __builtin_amdgcn_s_barrier();
    if (ks + 2 < NK) STAGE1(ks + 2, cur);
    cur ^= 1;
  }

  int lr = (lane >> 4) * 4, lc = lane & 15;
#pragma unroll
  for (int j = 0; j < 4; j++) {
    int col = nt * 128 + wc * 64 + j * 16 + lc;
    float bias = b1[e * D_HID + col];
#pragma unroll
    for (int i = 0; i < 4; i++) {
#pragma unroll
      for (int r = 0; r < 4; r++) {
        int grow = mt * 128 + wr * 64 + i * 16 + lr + r;
        if (grow < ce) {
          float v = fmaxf(acc[i][j][r] + bias, 0.f);
          H[(size_t)(off + grow) * D_HID + col] = (short)f2bf(v);
        }
      }
    }
  }
}

// ------------------------------------------------------------------ GEMM2 ----
// K-split x2 (each block K=2048) -> 512 active blocks = 2/CU. Partials to Y halves.
__global__ __launch_bounds__(256) void gemm2_kernel(
    const short* __restrict__ H,    // [4096][4096] bf16
    const short* __restrict__ W2b,  // [8][1024][4096] bf16 (n-major)
    const int* __restrict__ cnt,
    float* __restrict__ Y) {        // [2][4096][1024] f32 partials
  const int NT_M = N_TOKENS / 128, NT_N = D_OUT / 128;
  const int PER_E = 2 * NT_M * NT_N;  // 256
  int bid0 = blockIdx.x;
  int bid = (bid0 & 7) * ((NE * PER_E) >> 3) + (bid0 >> 3);
  int e = bid / PER_E;
  int r2 = bid % PER_E;
  int kh = r2 / (NT_M * NT_N);
  int r3 = r2 % (NT_M * NT_N);
  int mt = r3 % NT_M, nt = r3 / NT_M;
  int ce = cnt[e];
  if (mt * 128 >= ce) return;
  int off = 0;
  for (int i = 0; i < e; i++) off += cnt[i];

  __shared__ alignas(16) short As[2][128][32];
  __shared__ alignas(16) short Bs[2][128][32];

  int lane = threadIdx.x & 63, wid = threadIdx.x >> 6;
  int wr = wid >> 1, wc = wid & 1;
  int srow = lane >> 2;
  int gch = ((lane & 3) ^ ((lane >> 3) & 3)) * 8;
  size_t kbase = (size_t)kh * 2048;

  const short* a_src[2];
  const short* b_src[2];
#pragma unroll
  for (int j = 0; j < 2; j++) {
    int r = (wid + 4 * j) * 16 + srow;
    int grow = mt * 128 + r;
    if (grow > ce - 1) grow = ce - 1;
    a_src[j] = H + (size_t)(off + grow) * D_HID + kbase + gch;
    b_src[j] = W2b + (size_t)e * D_OUT * D_HID + (size_t)(nt * 128 + r) * D_HID + kbase + gch;
  }

  f32x4 zero = {0.f, 0.f, 0.f, 0.f};
  f32x4 acc[4][4];
#pragma unroll
  for (int i = 0; i < 4; i++)
#pragma unroll
    for (int j = 0; j < 4; j++) acc[i][j] = zero;

#define STAGE2(ks, buf)                                                         \
  {                                                                             \
    int k0 = (ks) * 32;                                                         \
    GLDS16(a_src[0] + k0, &As[buf][wid * 16][0]);                               \
    GLDS16(a_src[1] + k0, &As[buf][(wid + 4) * 16][0]);                         \
    GLDS16(b_src[0] + k0, &Bs[buf][wid * 16][0]);                               \
    GLDS16(b_src[1] + k0, &Bs[buf][(wid + 4) * 16][0]);                         \
  }

  const int NK = 2048 / 32;  // 64
  STAGE2(0, 0);
  STAGE2(1, 1);
  int cur = 0;
  int chsh = (((lane >> 4) ^ ((lane >> 1) & 3)) & 3) * 8;
  int arow = wr * 64 + (lane & 15), brow = wc * 64 + (lane & 15);
  for (int ks = 0; ks < NK; ks++) {
    if (ks + 1 < NK) asm volatile("s_waitcnt vmcnt(4)" : : : "memory");
    else             asm volatile("s_waitcnt vmcnt(0)" : : : "memory");
    __builtin_amdgcn_s_barrier();
    s16x8 a[4], b[4];
#pragma unroll
    for (int i = 0; i < 4; i++)
      a[i] = *(const s16x8*)&As[cur][arow + i * 16][chsh];
#pragma unroll
    for (int j = 0; j < 4; j++)
      b[j] = *(const s16x8*)&Bs[cur][brow + j * 16][chsh];
#pragma unroll
    for (int i = 0; i < 4; i++)
#pragma unroll
      for (int j = 0; j < 4; j++)
        acc[i][j] = __builtin_amdgcn_mfma_f32_16x16x32_bf16(a[i], b[j], acc[i][j], 0, 0, 0);
    __builtin_amdgcn_s_barrier();
    if (ks + 2 < NK) STAGE2(ks + 2, cur);
    cur ^= 1;
  }

  float* Yh = Y + (size_t)kh * (2 * N_TOKENS) * D_OUT;
  int lr = (lane >> 4) * 4, lc = lane & 15;
#pragma unroll
  for (int j = 0; j < 4; j++) {
    int col = nt * 128 + wc * 64 + j * 16 + lc;
#pragma unroll
    for (int i = 0; i < 4; i++) {
#pragma unroll
      for (int r = 0; r < 4; r++) {
        int grow = mt * 128 + wr * 64 + i * 16 + lr + r;
        if (grow < ce) Yh[(size_t)(off + grow) * D_OUT + col] = acc[i][j][r];
      }
    }
  }
}

// ---------------------------------------------------------------- combine ----
__global__ __launch_bounds__(256) void combine_kernel(
    const float* __restrict__ Y, const float* __restrict__ b2,
    const int* __restrict__ cnt, const int4* __restrict__ meta,
    const float2* __restrict__ tw, float* __restrict__ out) {
  const size_t YH = (size_t)(2 * N_TOKENS) * D_OUT;
  int n = blockIdx.x;
  int4 m = meta[n];
  float2 w = tw[n];
  int off0 = 0, off1 = 0;
#pragma unroll
  for (int i = 0; i < NE; i++) {
    int c = cnt[i];
    if (i < m.x) off0 += c;
    if (i < m.z) off1 += c;
  }
  size_t r0 = (size_t)(off0 + m.y) * D_OUT;
  size_t r1 = (size_t)(off1 + m.w) * D_OUT;
  const float4* y0a = (const float4*)(Y + r0);
  const float4* y0b = (const float4*)(Y + YH + r0);
  const float4* y1a = (const float4*)(Y + r1);
  const float4* y1b = (const float4*)(Y + YH + r1);
  const float4* g0 = (const float4*)(b2 + (size_t)m.x * D_OUT);
  const float4* g1 = (const float4*)(b2 + (size_t)m.z * D_OUT);
  float4* o = (float4*)(out + (size_t)n * D_OUT);
  int d = threadIdx.x;
  float4 a0 = y0a[d], a1 = y0b[d], b0 = y1a[d], b1v = y1b[d];
  float4 ba = g0[d], bb = g1[d];
  float4 r;
  r.x = w.x * (a0.x + a1.x + ba.x) + w.y * (b0.x + b1v.x + bb.x);
  r.y = w.x * (a0.y + a1.y + ba.y) + w.y * (b0.y + b1v.y + bb.y);
  r.z = w.x * (a0.z + a1.z + ba.z) + w.y * (b0.z + b1v.z + bb.z);
  r.w = w.x * (a0.w + a1.w + ba.w) + w.y * (b0.w + b1v.w + bb.w);
  o[d] = r;
}

// ----------------------------------------------------------------- launch ----
extern "C" void kernel_launch(void* const* d_in, const int* in_sizes, int n_in,
                              void* d_out, int out_size, void* d_ws, size_t ws_size,
                              hipStream_t stream) {
  const float* x  = (const float*)d_in[0];
  const float* Wr = (const float*)d_in[1];
  const float* br = (const float*)d_in[2];
  const float* W1 = (const float*)d_in[3];
  const float* b1 = (const float*)d_in[4];
  const float* W2 = (const float*)d_in[5];
  const float* b2 = (const float*)d_in[6];
  float* out = (float*)d_out;

  char* ws = (char*)d_ws;
  size_t o = 0;
  auto alloc = [&](size_t bytes) -> void* {
    o = (o + 255) & ~(size_t)255;
    void* p = ws + o;
    o += bytes;
    return p;
  };
  int*    cnt  = (int*)alloc(NE * 4);
  int*    tids = (int*)alloc((size_t)NE * N_TOKENS * 4);
  int4*   meta = (int4*)alloc((size_t)N_TOKENS * 16);
  float2* tw   = (float2*)alloc((size_t)N_TOKENS * 8);
  short*  xb   = (short*)alloc((size_t)N_TOKENS * D_IN * 2);
  short*  W1b  = (short*)alloc((size_t)NE * D_HID * D_IN * 2);
  short*  W2b  = (short*)alloc((size_t)NE * D_OUT * D_HID * 2);
  short*  H    = (short*)alloc((size_t)2 * N_TOKENS * D_HID * 2);
  float*  Y    = (float*)alloc((size_t)2 * 2 * N_TOKENS * D_OUT * 4);  // 2 K-halves
  if (o > ws_size) return;  // workspace too small; fail loudly via wrong output

  hipMemsetAsync(cnt, 0, NE * 4, stream);
  router_kernel<<<N_TOKENS / 4, 256, 0, stream>>>(x, Wr, br, cnt, tids, meta, tw);
  convx_kernel<<<(N_TOKENS * D_IN / 4) / 256, 256, 0, stream>>>(x, xb);
  transconv_kernel<<<dim3(D_HID / 64, D_IN / 64, NE), 256, 0, stream>>>(W1, W1b, D_IN, D_HID);
  transconv_kernel<<<dim3(D_OUT / 64, D_HID / 64, NE), 256, 0, stream>>>(W2, W2b, D_HID, D_OUT);
  gemm1_kernel<<<NE * (N_TOKENS / 128) * (D_HID / 128), 256, 0, stream>>>(xb, W1b, b1, cnt, tids, H);
  gemm2_kernel<<<NE * (N_TOKENS / 128) * (D_OUT / 128) * 2, 256, 0, stream>>>(H, W2b, cnt, Y);
  combine_kernel<<<N_TOKENS, 256, 0, stream>>>(Y, b2, cnt, meta, tw, out);
}